// Round 1
// 198.155 us; speedup vs baseline: 1.0720x; 1.0720x over previous
//
#include <hip/hip_runtime.h>
#include <hip/hip_bf16.h>
#include <math.h>

// Problem constants: B=8, C=256, CQ=32, N=H*W=4096
constexpr int B_ = 8;
constexpr int C_ = 256;
constexpr int CQ_ = 32;
constexpr int N_ = 4096;
constexpr int NT = 64;            // n-tile
constexpr int TILES = N_ / NT;    // 64
constexpr int FP = 40;            // padded pitch (shorts) for 32-wide rows: bank-clean

typedef __attribute__((ext_vector_type(8))) short short8;   // 8 bf16
typedef __attribute__((ext_vector_type(4))) float f32x4;    // MFMA C/D

__device__ __forceinline__ unsigned short pk1(float a) {
    __hip_bfloat16 h = __float2bfloat16(a);
    return *reinterpret_cast<unsigned short*>(&h);
}
__device__ __forceinline__ unsigned pk2(float a, float b) {
    __hip_bfloat162 h = __float22bfloat162_rn(float2{a, b});
    return *reinterpret_cast<unsigned*>(&h);
}

// async global->LDS, 16B per lane (dest = wave-uniform base + lane*16)
__device__ __forceinline__ void async16(const unsigned short* g, unsigned short* l) {
    __builtin_amdgcn_global_load_lds(
        (const __attribute__((address_space(1))) unsigned int*)g,
        (__attribute__((address_space(3))) unsigned int*)l, 16, 0, 0);
}

// ---------------------------------------------------------------------------
// prep (merged): blocks 0..2047 transpose feat -> featT [b][ks][n][ci&31] pitch 40;
// blocks 2048..2079: w1/w2 -> wqk pitch 264 ; w3 -> w3t [ks][c][ci&31] pitch 40
// ---------------------------------------------------------------------------
__global__ __launch_bounds__(256) void prep(
    const float* __restrict__ feat,
    const float* __restrict__ w1, const float* __restrict__ w2,
    const float* __restrict__ w3,
    unsigned short* __restrict__ featT,
    unsigned short* __restrict__ wqk, unsigned short* __restrict__ w3t)
{
    __shared__ float sh[64][65];
    int id = blockIdx.x;
    int t = threadIdx.x;

    if (id < 2048) {
        int b = id >> 8, r = id & 255;
        int n0 = (r >> 2) * 64, c0 = (r & 3) * 64;
        int nl = t & 63, cb = t >> 6;
#pragma unroll
        for (int i = 0; i < 16; ++i) {
            int cl = cb + i * 4;
            sh[cl][nl] = feat[((size_t)b * C_ + c0 + cl) * N_ + n0 + nl];
        }
        __syncthreads();
        int c2 = (t & 31) * 2, nb = t >> 5;
#pragma unroll
        for (int j = 0; j < 8; ++j) {
            int n = nb + j * 8;
            unsigned pv = pk2(sh[c2][n], sh[c2 + 1][n]);
            int cg = c0 + c2;
            int ks = cg >> 5, cij = cg & 31;
            *reinterpret_cast<unsigned*>(
                &featT[(((size_t)b * 8 + ks) * N_ + n0 + n) * FP + cij]) = pv;
        }
    } else {
        int tid = (id - 2048) * 256 + t;
        const int stride = 32 * 256;
        for (int f = tid; f < 2 * 32 * 256; f += stride) {
            int mat = f >> 13, rest = f & 8191;
            int o = rest >> 8, ci = rest & 255;
            const float* w = mat ? w2 : w1;
            wqk[(mat * 32 + o) * 264 + ci] = pk1(w[o * 256 + ci]);
        }
        for (int f = tid; f < 256 * 256; f += stride) {
            int c = f >> 8, ci = f & 255;
            w3t[((size_t)(ci >> 5) * 256 + c) * FP + (ci & 31)] = pk1(w3[f]);
        }
    }
}

// ---------------------------------------------------------------------------
// proj (merged): blocks 0..255 = qk (b=id>>5, 128 n rows);
//                blocks 256..767 = v (b, 64-n tile).
// v output is written FRAGMENT-PACKED for attn:
//   vws[(b*TILES+tile)*16384 + (cg*2+h)*512 + grp*128 + ccol*8 + j]
//     = V[c = cg*16+ccol][n = h*32+grp*8+j]   (one 16x32 A-fragment = 512 shorts,
//       laid out so a wave's 64 lanes read it as ONE contiguous 1KiB dwordx4 load)
// ---------------------------------------------------------------------------
__global__ __launch_bounds__(256) void proj(
    const unsigned short* __restrict__ featT, const unsigned short* __restrict__ wqk,
    const unsigned short* __restrict__ w3t,
    const float* __restrict__ b1, const float* __restrict__ b2,
    const float* __restrict__ b3,
    unsigned short* __restrict__ qT, unsigned short* __restrict__ kws,
    unsigned short* __restrict__ vws)
{
    __shared__ __align__(16) unsigned short smem[23552];   // 47,104 B
    int id = blockIdx.x;
    int t = threadIdx.x, lane = t & 63;
    int wu = t >> 6, col = lane & 15, grp = lane >> 4;

    if (id < 256) {
        // ---------------- qk branch ----------------
        unsigned short* wsl = smem;           // 18,432 shorts (pitch 264)
        unsigned short* fa  = smem + 18432;   //  5,120 shorts (128 rows x 40)
        int b = id >> 5, n0 = (id & 31) * 128;

#pragma unroll
        for (int i = 0; i < 9; ++i)
            async16(wqk + wu * 4608 + i * 512 + lane * 8, wsl + wu * 4608 + i * 512);

        f32x4 acc[2][2][2];  // [msub][mat][ot]
#pragma unroll
        for (int ms = 0; ms < 2; ++ms)
#pragma unroll
            for (int ot = 0; ot < 2; ++ot) {
                float bq = b1[ot * 16 + col];
                float bk = b2[ot * 16 + col];
                acc[ms][0][ot] = (f32x4){bq, bq, bq, bq};
                acc[ms][1][ot] = (f32x4){bk, bk, bk, bk};
            }

        for (int ks = 0; ks < 8; ++ks) {
            __syncthreads();
            const unsigned short* src = featT + (((size_t)b * 8 + ks) * N_ + n0) * FP;
            // 128*40 = 5120 shorts = 10 chunks of 512
#pragma unroll
            for (int i = 0; i < 3; ++i) {
                int ch = i * 4 + wu;
                if (ch < 10) async16(src + ch * 512 + lane * 8, fa + ch * 512);
            }
            __syncthreads();

            short8 a[2], bf[2][2];
#pragma unroll
            for (int ms = 0; ms < 2; ++ms)
                a[ms] = *(const short8*)&fa[(wu * 32 + ms * 16 + col) * FP + grp * 8];
#pragma unroll
            for (int mat = 0; mat < 2; ++mat)
#pragma unroll
                for (int ot = 0; ot < 2; ++ot)
                    bf[mat][ot] = *(const short8*)
                        &wsl[(mat * 32 + ot * 16 + col) * 264 + ks * 32 + grp * 8];
#pragma unroll
            for (int ms = 0; ms < 2; ++ms)
#pragma unroll
                for (int mat = 0; mat < 2; ++mat)
#pragma unroll
                    for (int ot = 0; ot < 2; ++ot)
                        acc[ms][mat][ot] = __builtin_amdgcn_mfma_f32_16x16x32_bf16(
                            a[ms], bf[mat][ot], acc[ms][mat][ot], 0, 0, 0);
        }

#pragma unroll
        for (int ms = 0; ms < 2; ++ms)
#pragma unroll
            for (int ot = 0; ot < 2; ++ot)
#pragma unroll
                for (int r = 0; r < 4; ++r) {
                    int n = n0 + wu * 32 + ms * 16 + grp * 4 + r;
                    int o = ot * 16 + col;
                    qT[((size_t)b * N_ + n) * 32 + o] = pk1(acc[ms][0][ot][r]);
                    kws[(((size_t)b * TILES + (n >> 6)) * 64 + (n & 63)) * FP + o]
                        = pk1(acc[ms][1][ot][r]);
                }
    } else {
        // ---------------- v branch ----------------
        unsigned short* w3s = smem;           // 10,240 shorts (256 rows x 40)
        unsigned short* fb  = smem + 10240;   //  2,560 shorts (64 rows x 40)
        int vid = id - 256;
        int b = vid >> 6, tile = vid & 63, n0 = tile * 64;

        f32x4 acc[4][4];  // [ct][nsub]
#pragma unroll
        for (int ct = 0; ct < 4; ++ct) {
            int c = wu * 64 + ct * 16 + grp * 4;
            float4 bb = *(const float4*)&b3[c];
            f32x4 ini = (f32x4){bb.x, bb.y, bb.z, bb.w};
#pragma unroll
            for (int ns = 0; ns < 4; ++ns) acc[ct][ns] = ini;
        }

        for (int ks = 0; ks < 8; ++ks) {
            __syncthreads();
            const unsigned short* wsrc = w3t + (size_t)ks * 256 * FP;
            // 256*40 = 10240 shorts = 20 chunks -> 5 per wave
#pragma unroll
            for (int i = 0; i < 5; ++i) {
                int ch = wu * 5 + i;
                async16(wsrc + ch * 512 + lane * 8, w3s + ch * 512);
            }
            const unsigned short* fsrc = featT + (((size_t)b * 8 + ks) * N_ + n0) * FP;
            // 64*40 = 2560 shorts = 5 chunks
#pragma unroll
            for (int i = 0; i < 2; ++i) {
                int ch = i * 4 + wu;
                if (ch < 5) async16(fsrc + ch * 512 + lane * 8, fb + ch * 512);
            }
            __syncthreads();

            short8 a[4], bfr[4];
#pragma unroll
            for (int ct = 0; ct < 4; ++ct)
                a[ct] = *(const short8*)&w3s[(wu * 64 + ct * 16 + col) * FP + grp * 8];
#pragma unroll
            for (int ns = 0; ns < 4; ++ns)
                bfr[ns] = *(const short8*)&fb[(ns * 16 + col) * FP + grp * 8];
#pragma unroll
            for (int ct = 0; ct < 4; ++ct)
#pragma unroll
                for (int ns = 0; ns < 4; ++ns)
                    acc[ct][ns] = __builtin_amdgcn_mfma_f32_16x16x32_bf16(
                        a[ct], bfr[ns], acc[ct][ns], 0, 0, 0);
        }

        // fragment-packed V epilogue (see header comment)
        unsigned short* vt = vws + ((size_t)b * TILES + tile) * 16384;
#pragma unroll
        for (int ct = 0; ct < 4; ++ct)
#pragma unroll
            for (int ns = 0; ns < 4; ++ns)
#pragma unroll
                for (int r = 0; r < 4; ++r) {
                    int c = wu * 64 + ct * 16 + grp * 4 + r;
                    int n = ns * 16 + col;
                    int cg = c >> 4, ccol = c & 15;
                    int h = n >> 5, ag = (n >> 3) & 3, j = n & 7;
                    vt[(cg * 2 + h) * 512 + ag * 128 + ccol * 8 + j]
                        = pk1(acc[ct][ns][r]);
                }
    }
}

// ---------------------------------------------------------------------------
// attn: flash attention, no-max softmax, MFMA both GEMMs.
// block = (b, 64 m), 4 waves; wave owns 64 channels in PV.
// V: DIRECT global->register fragments (no LDS), prefetched one full tile ahead.
// K: LDS double-buffer via global_load_lds, issued one full tile ahead.
// ps: double-buffered -> ONE __syncthreads per tile.
// ---------------------------------------------------------------------------
__global__ __launch_bounds__(256, 2) void attn(
    const unsigned short* __restrict__ qT, const unsigned short* __restrict__ kws,
    const unsigned short* __restrict__ vws, const float* __restrict__ feat,
    const float* __restrict__ gamma, float* __restrict__ out)
{
    __shared__ __align__(16) unsigned short ks2[2][64 * FP];  // 10,240 B
    __shared__ __align__(16) unsigned short ps[2][64 * 72];   // 18,432 B
    __shared__ float lrow[64];

    const int b = blockIdx.x, m0 = blockIdx.y * 64;
    const int t = threadIdx.x, lane = t & 63;
    const int wu = t >> 6, col = lane & 15, grp = lane >> 4;

    const int m_own = m0 + wu * 16 + col;   // this wave's S column
    const short8 qf = *(const short8*)&qT[((size_t)b * N_ + m_own) * 32 + grp * 8];

    f32x4 acc[4][4];  // [ct][msub]
#pragma unroll
    for (int i = 0; i < 4; ++i)
#pragma unroll
        for (int j = 0; j < 4; ++j) acc[i][j] = (f32x4){0.f, 0.f, 0.f, 0.f};
    float l_run = 0.f;

    const unsigned short* kbase = kws + (size_t)b * TILES * 64 * FP;
    // wave's V fragment base: fragments (ct,h) of this wave's 64 channels.
    // fragment (tt,ct,h) = 16B/lane contiguous 1KiB at vfb + tt*16384 + (ct*2+h)*512
    const unsigned short* vfb =
        vws + ((size_t)b * TILES * 32 + (size_t)wu * 8) * 512 + lane * 8;

    short8 va[4][2], vb[4][2];

#define STAGEK(tt) do {                                                        \
    if ((tt) < TILES) {                                                        \
        const unsigned short* src_ = kbase + (size_t)(tt) * (64 * FP);         \
        unsigned short* dst_ = ks2[(tt) & 1];                                  \
        _Pragma("unroll")                                                      \
        for (int i_ = 0; i_ < 2; ++i_) {                                       \
            int ch_ = i_ * 4 + wu;                                             \
            if (ch_ < 5) async16(src_ + ch_ * 512 + lane * 8, dst_ + ch_ * 512); \
        }                                                                      \
    }                                                                          \
} while (0)

#define LOADV(tt, VR) do {                                                     \
    const unsigned short* p_ = vfb + (size_t)(tt) * 16384;                     \
    _Pragma("unroll")                                                          \
    for (int ct_ = 0; ct_ < 4; ++ct_)                                          \
        _Pragma("unroll")                                                      \
        for (int h_ = 0; h_ < 2; ++h_)                                         \
            VR[ct_][h_] = *(const short8*)&p_[(ct_ * 2 + h_) * 512];           \
} while (0)

#define DOS(tt) do {                                                           \
    const unsigned short* kc_ = ks2[(tt) & 1];                                 \
    f32x4 z_ = (f32x4){0.f, 0.f, 0.f, 0.f};                                    \
    f32x4 d_[4];                                                               \
    _Pragma("unroll")                                                          \
    for (int sub_ = 0; sub_ < 4; ++sub_) {                                     \
        short8 a_ = *(const short8*)&kc_[(sub_ * 16 + col) * FP + grp * 8];    \
        d_[sub_] = __builtin_amdgcn_mfma_f32_16x16x32_bf16(a_, qf, z_, 0, 0, 0); \
    }                                                                          \
    float ptot_ = 0.f;                                                         \
    unsigned short* pw_ = ps[(tt) & 1];                                        \
    _Pragma("unroll")                                                          \
    for (int sub_ = 0; sub_ < 4; ++sub_) {                                     \
        float p0 = __expf(d_[sub_][0]);                                        \
        float p1 = __expf(d_[sub_][1]);                                        \
        float p2 = __expf(d_[sub_][2]);                                        \
        float p3 = __expf(d_[sub_][3]);                                        \
        ptot_ += (p0 + p1) + (p2 + p3);                                        \
        uint2 w_;                                                              \
        w_.x = pk2(p0, p1);                                                    \
        w_.y = pk2(p2, p3);                                                    \
        *reinterpret_cast<uint2*>(                                             \
            &pw_[(wu * 16 + col) * 72 + sub_ * 16 + grp * 4]) = w_;            \
    }                                                                          \
    ptot_ += __shfl_xor(ptot_, 16);                                            \
    ptot_ += __shfl_xor(ptot_, 32);                                            \
    l_run += ptot_;                                                            \
} while (0)

#define DOPV(tt, VR) do {                                                      \
    const unsigned short* pp_ = ps[(tt) & 1];                                  \
    short8 pf_[4][2];                                                          \
    _Pragma("unroll")                                                          \
    for (int ms_ = 0; ms_ < 4; ++ms_)                                          \
        _Pragma("unroll")                                                      \
        for (int h_ = 0; h_ < 2; ++h_)                                         \
            pf_[ms_][h_] = *(const short8*)                                    \
                &pp_[(ms_ * 16 + col) * 72 + h_ * 32 + grp * 8];               \
    _Pragma("unroll")                                                          \
    for (int ct_ = 0; ct_ < 4; ++ct_) {                                        \
        _Pragma("unroll")                                                      \
        for (int ms_ = 0; ms_ < 4; ++ms_)                                      \
            acc[ct_][ms_] = __builtin_amdgcn_mfma_f32_16x16x32_bf16(           \
                VR[ct_][0], pf_[ms_][0], acc[ct_][ms_], 0, 0, 0);              \
        _Pragma("unroll")                                                      \
        for (int ms_ = 0; ms_ < 4; ++ms_)                                      \
            acc[ct_][ms_] = __builtin_amdgcn_mfma_f32_16x16x32_bf16(           \
                VR[ct_][1], pf_[ms_][1], acc[ct_][ms_], 0, 0, 0);              \
    }                                                                          \
} while (0)

    // prologue: K[0] staged + drained
    STAGEK(0);
    __syncthreads();

    // body 0 (no PV yet): stage K[1], prefetch V[0], S(0)
    STAGEK(1);
    LOADV(0, va);
    DOS(0);
    __syncthreads();   // drains K[1] + V[0]; ps[0] visible

    for (int tt = 1; tt < TILES; tt += 2) {
        // ---- tile tt ----
        STAGEK(tt + 1);                    // -> ks2[(tt+1)&1], drained below
        LOADV(tt, vb);                     // V[tt] regs, drained below
        DOPV(tt - 1, va);                  // reads ps[(tt-1)&1]
        DOS(tt);                           // writes ps[tt&1]
        __syncthreads();

        // ---- tile tt+1 ----
        STAGEK(tt + 2);
        if (tt + 1 < TILES) LOADV(tt + 1, va);
        DOPV(tt, vb);
        if (tt + 1 < TILES) DOS(tt + 1);
        __syncthreads();
    }

#undef STAGEK
#undef LOADV
#undef DOS
#undef DOPV

    if (grp == 0) lrow[wu * 16 + col] = l_run;
    __syncthreads();

    const float g = gamma[0];
#pragma unroll
    for (int ms = 0; ms < 4; ++ms) {
        float rl = 1.f / lrow[ms * 16 + col];
        int m = m0 + ms * 16 + col;
#pragma unroll
        for (int ct = 0; ct < 4; ++ct)
#pragma unroll
            for (int r = 0; r < 4; ++r) {
                int c = wu * 64 + ct * 16 + grp * 4 + r;
                size_t idx = ((size_t)b * C_ + c) * N_ + m;
                out[idx] = g * acc[ct][ms][r] * rl + feat[idx];
            }
    }
}

// ---------------------------------------------------------------------------
extern "C" void kernel_launch(void* const* d_in, const int* in_sizes, int n_in,
                              void* d_out, int out_size, void* d_ws, size_t ws_size,
                              hipStream_t stream)
{
    (void)in_sizes; (void)n_in; (void)out_size; (void)ws_size;
    const float* feat  = (const float*)d_in[0];
    const float* w1    = (const float*)d_in[1];
    const float* b1    = (const float*)d_in[2];
    const float* w2    = (const float*)d_in[3];
    const float* b2    = (const float*)d_in[4];
    const float* w3    = (const float*)d_in[5];
    const float* b3    = (const float*)d_in[6];
    const float* gamma = (const float*)d_in[7];
    float* out = (float*)d_out;

    // ws carve (shorts):
    // featT 10,485,760 | wqk 18,432 | w3t 81,920 | qT 1,048,576
    // kws 1,310,720 | vws 8,388,608  => 21,334,016 shorts = 42.7 MB
    unsigned short* featT = (unsigned short*)d_ws;
    unsigned short* wqk   = featT + (size_t)B_ * 8 * N_ * FP;
    unsigned short* w3t   = wqk + 18432;
    unsigned short* qT    = w3t + (size_t)8 * 256 * FP;
    unsigned short* kws   = qT + (size_t)B_ * N_ * 32;
    unsigned short* vws   = kws + (size_t)B_ * TILES * 64 * FP;

    prep<<<2048 + 32, 256, 0, stream>>>(feat, w1, w2, w3, featT, wqk, w3t);
    proj<<<768, 256, 0, stream>>>(featT, wqk, w3t, b1, b2, b3, qT, kws, vws);
    attn<<<dim3(B_, N_ / 64), 256, 0, stream>>>(qT, kws, vws, feat, gamma, out);
}

// Round 2
// 186.813 us; speedup vs baseline: 1.1371x; 1.0607x over previous
//
#include <hip/hip_runtime.h>
#include <hip/hip_bf16.h>
#include <math.h>

// Problem constants: B=8, C=256, CQ=32, N=H*W=4096
constexpr int B_ = 8;
constexpr int C_ = 256;
constexpr int CQ_ = 32;
constexpr int N_ = 4096;
constexpr int NT = 64;            // n-tile
constexpr int TILES = N_ / NT;    // 64

// Everything LDS-resident is FRAGMENT-PACKED: a 16x32 bf16 MFMA operand tile
// is stored as one contiguous 1KiB block; lane L reads its 16B at L*16.
// ds_read_b128 is then a linear 64-lane x 16B stream: zero bank conflicts.

typedef __attribute__((ext_vector_type(8))) short short8;   // 8 bf16
typedef __attribute__((ext_vector_type(4))) float f32x4;    // MFMA C/D

constexpr float LOG2E = 1.44269504088896340736f;

__device__ __forceinline__ unsigned short pk1(float a) {
    __hip_bfloat16 h = __float2bfloat16(a);
    return *reinterpret_cast<unsigned short*>(&h);
}
__device__ __forceinline__ unsigned pk2(float a, float b) {
    __hip_bfloat162 h = __float22bfloat162_rn(float2{a, b});
    return *reinterpret_cast<unsigned*>(&h);
}

// async global->LDS, 16B per lane (dest = wave-uniform base + lane*16)
__device__ __forceinline__ void async16(const unsigned short* g, unsigned short* l) {
    __builtin_amdgcn_global_load_lds(
        (const __attribute__((address_space(1))) unsigned int*)g,
        (__attribute__((address_space(3))) unsigned int*)l, 16, 0, 0);
}

// ---------------------------------------------------------------------------
// Fragment-packed layouts (shorts):
//  featT: F(b,ks,n,ci) = ((b*8+ks)*N + (n&~15))*32 + ((ci>>3)*16 + (n&15))*8 + (ci&7)
//         (A/B-operand frags of 16 n x 32 ci, 512 shorts each, n-major)
//  wqk:   (ci>>5)*2048 + (mat*2 + (o>>4))*512 + (((ci&31)>>3)*16 + (o&15))*8 + (ci&7)
//  w3t:   (ci>>5)*8192 + (c>>4)*512 + (((ci&31)>>3)*16 + (c&15))*8 + (ci&7)
//  kws:   ((b*TILES+tile)*4 + ((n&63)>>4))*512 + ((o>>3)*16 + (n&15))*8 + (o&7)
//  vws:   (b*TILES+tile)*16384 + (cg*2+h)*512 + ag*128 + ccol*8 + j   (unchanged)
// ---------------------------------------------------------------------------

// ---------------------------------------------------------------------------
// prep (merged): blocks 0..2047 transpose feat -> featT (fragment-packed);
// blocks 2048..2079: w1/w2 -> wqk ; w3 -> w3t (both fragment-packed)
// ---------------------------------------------------------------------------
__global__ __launch_bounds__(256) void prep(
    const float* __restrict__ feat,
    const float* __restrict__ w1, const float* __restrict__ w2,
    const float* __restrict__ w3,
    unsigned short* __restrict__ featT,
    unsigned short* __restrict__ wqk, unsigned short* __restrict__ w3t)
{
    __shared__ float sh[64][65];
    int id = blockIdx.x;
    int t = threadIdx.x;

    if (id < 2048) {
        int b = id >> 8, r = id & 255;
        int n0 = (r >> 2) * 64, c0 = (r & 3) * 64;
        int nl = t & 63, cb = t >> 6;
#pragma unroll
        for (int i = 0; i < 16; ++i) {
            int cl = cb + i * 4;
            sh[cl][nl] = feat[((size_t)b * C_ + c0 + cl) * N_ + n0 + nl];
        }
        __syncthreads();
        int c2 = (t & 31) * 2, nb = t >> 5;
#pragma unroll
        for (int j = 0; j < 8; ++j) {
            int n = nb + j * 8;
            int ng = n0 + n;
            unsigned pv = pk2(sh[c2][n], sh[c2 + 1][n]);
            int cg = c0 + c2;
            int ks = cg >> 5, cij = cg & 31;
            size_t base = (((size_t)b * 8 + ks) * N_ + (ng & ~15)) * 32;
            int off = ((cij >> 3) * 16 + (ng & 15)) * 8 + (cij & 7);
            *reinterpret_cast<unsigned*>(&featT[base + off]) = pv;
        }
    } else {
        int tid = (id - 2048) * 256 + t;
        const int stride = 32 * 256;
        for (int f = tid; f < 2 * 32 * 256; f += stride) {
            int mat = f >> 13, rest = f & 8191;
            int o = rest >> 8, ci = rest & 255;
            const float* w = mat ? w2 : w1;
            wqk[(ci >> 5) * 2048 + (mat * 2 + (o >> 4)) * 512
                + (((ci & 31) >> 3) * 16 + (o & 15)) * 8 + (ci & 7)]
                = pk1(w[o * 256 + ci]);
        }
        for (int f = tid; f < 256 * 256; f += stride) {
            int c = f >> 8, ci = f & 255;
            w3t[(size_t)(ci >> 5) * 8192 + (c >> 4) * 512
                + (((ci & 31) >> 3) * 16 + (c & 15)) * 8 + (ci & 7)]
                = pk1(w3[f]);
        }
    }
}

// ---------------------------------------------------------------------------
// proj (merged, single-barrier double-buffered pipelines):
//  blocks 0..255 = qk (b=id>>5, 128 n rows); blocks 256..767 = v (b, 64-n tile)
// ---------------------------------------------------------------------------
__global__ __launch_bounds__(256) void proj(
    const unsigned short* __restrict__ featT, const unsigned short* __restrict__ wqk,
    const unsigned short* __restrict__ w3t,
    const float* __restrict__ b1, const float* __restrict__ b2,
    const float* __restrict__ b3,
    unsigned short* __restrict__ qT, unsigned short* __restrict__ kws,
    unsigned short* __restrict__ vws)
{
    __shared__ __align__(16) unsigned short smem[24576];   // 49,152 B
    int id = blockIdx.x;
    int t = threadIdx.x, lane = t & 63;
    int wu = t >> 6, col = lane & 15, grp = lane >> 4;

    if (id < 256) {
        // ---------------- qk branch ----------------
        unsigned short* wsl = smem;            // 16,384 shorts (all 8 ks frags)
        unsigned short* fab = smem + 16384;    // 2 x 4,096 shorts (128n x 32ci)
        int b = id >> 5, n0 = (id & 31) * 128;

#pragma unroll
        for (int i = 0; i < 8; ++i)
            async16(wqk + (wu * 8 + i) * 512 + lane * 8, wsl + (wu * 8 + i) * 512);
        {
            const unsigned short* src = featT + ((size_t)b * 8 * N_ + n0) * 32;
#pragma unroll
            for (int i = 0; i < 2; ++i)
                async16(src + (wu * 2 + i) * 512 + lane * 8, fab + (wu * 2 + i) * 512);
        }

        f32x4 acc[2][2][2];  // [msub][mat][ot]
#pragma unroll
        for (int ms = 0; ms < 2; ++ms)
#pragma unroll
            for (int ot = 0; ot < 2; ++ot) {
                float bq = b1[ot * 16 + col];
                float bk = b2[ot * 16 + col];
                acc[ms][0][ot] = (f32x4){bq, bq, bq, bq};
                acc[ms][1][ot] = (f32x4){bk, bk, bk, bk};
            }
        __syncthreads();

        for (int ks = 0; ks < 8; ++ks) {
            if (ks + 1 < 8) {
                const unsigned short* src =
                    featT + (((size_t)b * 8 + ks + 1) * N_ + n0) * 32;
                unsigned short* dst = fab + ((ks + 1) & 1) * 4096;
#pragma unroll
                for (int i = 0; i < 2; ++i)
                    async16(src + (wu * 2 + i) * 512 + lane * 8, dst + (wu * 2 + i) * 512);
            }
            const unsigned short* cur = fab + (ks & 1) * 4096;

            short8 a[2], bf[2][2];
#pragma unroll
            for (int ms = 0; ms < 2; ++ms)
                a[ms] = *(const short8*)&cur[(wu * 2 + ms) * 512 + lane * 8];
#pragma unroll
            for (int mat = 0; mat < 2; ++mat)
#pragma unroll
                for (int ot = 0; ot < 2; ++ot)
                    bf[mat][ot] = *(const short8*)
                        &wsl[ks * 2048 + (mat * 2 + ot) * 512 + lane * 8];
#pragma unroll
            for (int ms = 0; ms < 2; ++ms)
#pragma unroll
                for (int mat = 0; mat < 2; ++mat)
#pragma unroll
                    for (int ot = 0; ot < 2; ++ot)
                        acc[ms][mat][ot] = __builtin_amdgcn_mfma_f32_16x16x32_bf16(
                            a[ms], bf[mat][ot], acc[ms][mat][ot], 0, 0, 0);
            __syncthreads();
        }

#pragma unroll
        for (int ms = 0; ms < 2; ++ms)
#pragma unroll
            for (int ot = 0; ot < 2; ++ot)
#pragma unroll
                for (int r = 0; r < 4; ++r) {
                    int n = n0 + wu * 32 + ms * 16 + grp * 4 + r;
                    int o = ot * 16 + col;
                    // q scaled by log2(e): attn uses exp2 directly
                    qT[((size_t)b * N_ + n) * 32 + o] = pk1(acc[ms][0][ot][r] * LOG2E);
                    kws[(((size_t)b * TILES + (n >> 6)) * 4 + ((n & 63) >> 4)) * 512
                        + ((o >> 3) * 16 + (n & 15)) * 8 + (o & 7)]
                        = pk1(acc[ms][1][ot][r]);
                }
    } else {
        // ---------------- v branch ----------------
        unsigned short* w3b = smem;            // 2 x 8,192 shorts (256c x 32ci)
        unsigned short* fbb = smem + 16384;    // 2 x 2,048 shorts (64n x 32ci)
        int vid = id - 256;
        int b = vid >> 6, tile = vid & 63, n0 = tile * 64;

        f32x4 acc[4][4];  // [ct][nsub]
#pragma unroll
        for (int ct = 0; ct < 4; ++ct) {
            int c = wu * 64 + ct * 16 + grp * 4;
            float4 bb = *(const float4*)&b3[c];
            f32x4 ini = (f32x4){bb.x, bb.y, bb.z, bb.w};
#pragma unroll
            for (int ns = 0; ns < 4; ++ns) acc[ct][ns] = ini;
        }

#pragma unroll
        for (int i = 0; i < 4; ++i)
            async16(w3t + (wu * 4 + i) * 512 + lane * 8, w3b + (wu * 4 + i) * 512);
        async16(featT + ((size_t)b * 8 * N_ + n0) * 32 + wu * 512 + lane * 8,
                fbb + wu * 512);
        __syncthreads();

        for (int ks = 0; ks < 8; ++ks) {
            if (ks + 1 < 8) {
                const unsigned short* wsrc = w3t + (size_t)(ks + 1) * 8192;
                unsigned short* wdst = w3b + ((ks + 1) & 1) * 8192;
#pragma unroll
                for (int i = 0; i < 4; ++i)
                    async16(wsrc + (wu * 4 + i) * 512 + lane * 8,
                            wdst + (wu * 4 + i) * 512);
                const unsigned short* fsrc =
                    featT + (((size_t)b * 8 + ks + 1) * N_ + n0) * 32;
                async16(fsrc + wu * 512 + lane * 8,
                        fbb + ((ks + 1) & 1) * 2048 + wu * 512);
            }
            const unsigned short* wcur = w3b + (ks & 1) * 8192;
            const unsigned short* fcur = fbb + (ks & 1) * 2048;

            short8 a[4], bfr[4];
#pragma unroll
            for (int ct = 0; ct < 4; ++ct)
                a[ct] = *(const short8*)&wcur[(wu * 4 + ct) * 512 + lane * 8];
#pragma unroll
            for (int ns = 0; ns < 4; ++ns)
                bfr[ns] = *(const short8*)&fcur[ns * 512 + lane * 8];
#pragma unroll
            for (int ct = 0; ct < 4; ++ct)
#pragma unroll
                for (int ns = 0; ns < 4; ++ns)
                    acc[ct][ns] = __builtin_amdgcn_mfma_f32_16x16x32_bf16(
                        a[ct], bfr[ns], acc[ct][ns], 0, 0, 0);
            __syncthreads();
        }

        // fragment-packed V epilogue (unchanged layout)
        unsigned short* vt = vws + ((size_t)b * TILES + tile) * 16384;
#pragma unroll
        for (int ct = 0; ct < 4; ++ct)
#pragma unroll
            for (int ns = 0; ns < 4; ++ns)
#pragma unroll
                for (int r = 0; r < 4; ++r) {
                    int c = wu * 64 + ct * 16 + grp * 4 + r;
                    int n = ns * 16 + col;
                    int cg = c >> 4, ccol = c & 15;
                    int h = n >> 5, ag = (n >> 3) & 3, j = n & 7;
                    vt[(cg * 2 + h) * 512 + ag * 128 + ccol * 8 + j]
                        = pk1(acc[ct][ns][r]);
                }
    }
}

// ---------------------------------------------------------------------------
// attn: flash attention, no-max softmax (exp2; q pre-scaled by log2e).
// block = (b, 64 m), 4 waves; wave owns 64 channels in PV.
// V: global->register fragments (no LDS). K: LDS dbuf (frag-packed, 4 chunks).
// P: frag-packed LDS, double-buffered -> one barrier per tile.
// All LDS reads are linear lane*16 -> zero bank conflicts.
// ---------------------------------------------------------------------------
__global__ __launch_bounds__(256, 2) void attn(
    const unsigned short* __restrict__ qT, const unsigned short* __restrict__ kws,
    const unsigned short* __restrict__ vws, const float* __restrict__ feat,
    const float* __restrict__ gamma, float* __restrict__ out)
{
    __shared__ __align__(16) unsigned short ks2[2][2048];  //  8,192 B
    __shared__ __align__(16) unsigned short ps[2][4096];   // 16,384 B
    __shared__ float lrow[64];

    const int b = blockIdx.x, m0 = blockIdx.y * 64;
    const int t = threadIdx.x, lane = t & 63;
    const int wu = t >> 6, col = lane & 15, grp = lane >> 4;

    const int m_own = m0 + wu * 16 + col;   // this wave's S column
    const short8 qf = *(const short8*)&qT[((size_t)b * N_ + m_own) * 32 + grp * 8];

    f32x4 acc[4][4];  // [ct][msub]
#pragma unroll
    for (int i = 0; i < 4; ++i)
#pragma unroll
        for (int j = 0; j < 4; ++j) acc[i][j] = (f32x4){0.f, 0.f, 0.f, 0.f};
    float l_run = 0.f;

    const unsigned short* kbase = kws + (size_t)b * TILES * 2048;
    // wave's V fragment base (fragment-packed vws, 16B/lane contiguous 1KiB)
    const unsigned short* vfb =
        vws + ((size_t)b * TILES * 32 + (size_t)wu * 8) * 512 + lane * 8;

    short8 va[4][2], vb[4][2];

#define STAGEK(tt) do {                                                        \
    if ((tt) < TILES) {                                                        \
        async16(kbase + (size_t)(tt) * 2048 + wu * 512 + lane * 8,             \
                ks2[(tt) & 1] + wu * 512);                                     \
    }                                                                          \
} while (0)

#define LOADV(tt, VR) do {                                                     \
    const unsigned short* p_ = vfb + (size_t)(tt) * 16384;                     \
    _Pragma("unroll")                                                          \
    for (int ct_ = 0; ct_ < 4; ++ct_)                                          \
        _Pragma("unroll")                                                      \
        for (int h_ = 0; h_ < 2; ++h_)                                         \
            VR[ct_][h_] = *(const short8*)&p_[(ct_ * 2 + h_) * 512];           \
} while (0)

#define DOS(tt) do {                                                           \
    const unsigned short* kc_ = ks2[(tt) & 1];                                 \
    f32x4 z_ = (f32x4){0.f, 0.f, 0.f, 0.f};                                    \
    f32x4 d_[4];                                                               \
    __builtin_amdgcn_s_setprio(1);                                             \
    _Pragma("unroll")                                                          \
    for (int sub_ = 0; sub_ < 4; ++sub_) {                                     \
        short8 a_ = *(const short8*)&kc_[sub_ * 512 + lane * 8];               \
        d_[sub_] = __builtin_amdgcn_mfma_f32_16x16x32_bf16(a_, qf, z_, 0, 0, 0); \
    }                                                                          \
    __builtin_amdgcn_s_setprio(0);                                             \
    float ptot_ = 0.f;                                                         \
    unsigned short* pw_ = ps[(tt) & 1];                                        \
    _Pragma("unroll")                                                          \
    for (int sub_ = 0; sub_ < 4; ++sub_) {                                     \
        float p0 = __builtin_amdgcn_exp2f(d_[sub_][0]);                        \
        float p1 = __builtin_amdgcn_exp2f(d_[sub_][1]);                        \
        float p2 = __builtin_amdgcn_exp2f(d_[sub_][2]);                        \
        float p3 = __builtin_amdgcn_exp2f(d_[sub_][3]);                        \
        ptot_ += (p0 + p1) + (p2 + p3);                                        \
        uint2 w_;                                                              \
        w_.x = pk2(p0, p1);                                                    \
        w_.y = pk2(p2, p3);                                                    \
        *reinterpret_cast<uint2*>(                                             \
            &pw_[(wu * 2 + (sub_ >> 1)) * 512                                  \
                 + (((sub_ & 1) * 2 + (grp >> 1)) * 16 + col) * 8              \
                 + (grp & 1) * 4]) = w_;                                       \
    }                                                                          \
    ptot_ += __shfl_xor(ptot_, 16);                                            \
    ptot_ += __shfl_xor(ptot_, 32);                                            \
    l_run += ptot_;                                                            \
} while (0)

#define DOPV(tt, VR) do {                                                      \
    const unsigned short* pp_ = ps[(tt) & 1];                                  \
    short8 pf_[4][2];                                                          \
    _Pragma("unroll")                                                          \
    for (int ms_ = 0; ms_ < 4; ++ms_)                                          \
        _Pragma("unroll")                                                      \
        for (int h_ = 0; h_ < 2; ++h_)                                         \
            pf_[ms_][h_] = *(const short8*)&pp_[(ms_ * 2 + h_) * 512 + lane * 8]; \
    __builtin_amdgcn_s_setprio(1);                                             \
    _Pragma("unroll")                                                          \
    for (int ct_ = 0; ct_ < 4; ++ct_) {                                        \
        _Pragma("unroll")                                                      \
        for (int ms_ = 0; ms_ < 4; ++ms_)                                      \
            acc[ct_][ms_] = __builtin_amdgcn_mfma_f32_16x16x32_bf16(           \
                VR[ct_][0], pf_[ms_][0], acc[ct_][ms_], 0, 0, 0);              \
        _Pragma("unroll")                                                      \
        for (int ms_ = 0; ms_ < 4; ++ms_)                                      \
            acc[ct_][ms_] = __builtin_amdgcn_mfma_f32_16x16x32_bf16(           \
                VR[ct_][1], pf_[ms_][1], acc[ct_][ms_], 0, 0, 0);              \
    }                                                                          \
    __builtin_amdgcn_s_setprio(0);                                             \
} while (0)

    // prologue: K[0] staged + drained
    STAGEK(0);
    __syncthreads();

    // body 0 (no PV yet): stage K[1], prefetch V[0], S(0)
    STAGEK(1);
    LOADV(0, va);
    DOS(0);
    __syncthreads();   // drains K[1] + V[0]; ps[0] visible

    for (int tt = 1; tt < TILES; tt += 2) {
        // ---- tile tt ----
        STAGEK(tt + 1);
        LOADV(tt, vb);
        DOPV(tt - 1, va);
        DOS(tt);
        __syncthreads();

        // ---- tile tt+1 ----
        STAGEK(tt + 2);
        if (tt + 1 < TILES) LOADV(tt + 1, va);
        DOPV(tt, vb);
        if (tt + 1 < TILES) DOS(tt + 1);
        __syncthreads();
    }

#undef STAGEK
#undef LOADV
#undef DOS
#undef DOPV

    if (grp == 0) lrow[wu * 16 + col] = l_run;
    __syncthreads();

    const float g = gamma[0];
#pragma unroll
    for (int ms = 0; ms < 4; ++ms) {
        float rl = 1.f / lrow[ms * 16 + col];
        int m = m0 + ms * 16 + col;
#pragma unroll
        for (int ct = 0; ct < 4; ++ct)
#pragma unroll
            for (int r = 0; r < 4; ++r) {
                int c = wu * 64 + ct * 16 + grp * 4 + r;
                size_t idx = ((size_t)b * C_ + c) * N_ + m;
                out[idx] = g * acc[ct][ms][r] * rl + feat[idx];
            }
    }
}

// ---------------------------------------------------------------------------
extern "C" void kernel_launch(void* const* d_in, const int* in_sizes, int n_in,
                              void* d_out, int out_size, void* d_ws, size_t ws_size,
                              hipStream_t stream)
{
    (void)in_sizes; (void)n_in; (void)out_size; (void)ws_size;
    const float* feat  = (const float*)d_in[0];
    const float* w1    = (const float*)d_in[1];
    const float* b1    = (const float*)d_in[2];
    const float* w2    = (const float*)d_in[3];
    const float* b2    = (const float*)d_in[4];
    const float* w3    = (const float*)d_in[5];
    const float* b3    = (const float*)d_in[6];
    const float* gamma = (const float*)d_in[7];
    float* out = (float*)d_out;

    // ws carve (shorts), all fragment-packed:
    // featT 8,388,608 | wqk 16,384 | w3t 65,536 | qT 1,048,576
    // kws 1,048,576 | vws 8,388,608  => 18,956,288 shorts = 37.9 MB
    unsigned short* featT = (unsigned short*)d_ws;
    unsigned short* wqk   = featT + (size_t)B_ * 8 * N_ * 32;
    unsigned short* w3t   = wqk + 16384;
    unsigned short* qT    = w3t + 65536;
    unsigned short* kws   = qT + (size_t)B_ * N_ * 32;
    unsigned short* vws   = kws + (size_t)B_ * TILES * 4 * 512;

    prep<<<2048 + 32, 256, 0, stream>>>(feat, w1, w2, w3, featT, wqk, w3t);
    proj<<<768, 256, 0, stream>>>(featT, wqk, w3t, b1, b2, b3, qT, kws, vws);
    attn<<<dim3(B_, N_ / 64), 256, 0, stream>>>(qT, kws, vws, feat, gamma, out);
}